// Round 3
// baseline (201.393 us; speedup 1.0000x reference)
//
#include <hip/hip_runtime.h>
#include <stdint.h>

#define NUM_CLASSES 16
#define HW (512 * 512)            // 262144 = 2^18 pixels per plane
#define NVEC (8 * HW / 4)         // 524,288 float4-groups total
#define HALF (NVEC / 2)           // 262,144 = 1024 blocks * 256 threads
#define HBLOCKS 1024

// Kernel 1: per-pixel argmax over 16 class planes + joint (pred,target)
// 16x16 histogram. Each thread handles 2 float4-groups (grid-strided apart so
// every load instruction is lane-dense / fully coalesced). Per-block LDS
// histogram, flushed with PLAIN stores to a per-block partial table — no
// global atomics, no workspace init required (poison-value independent).
__global__ __launch_bounds__(256) void jaccard_hist_kernel(
    const float* __restrict__ pred,
    const int* __restrict__ target,
    unsigned int* __restrict__ parts) {
  __shared__ unsigned int lh[256];
  lh[threadIdx.x] = 0u;  // 256 threads cover 256 bins
  __syncthreads();

  int tid = blockIdx.x * 256 + threadIdx.x;  // 0..HALF-1

#pragma unroll
  for (int half = 0; half < 2; ++half) {
    int i = tid + half * HALF;         // float4-group index, exact coverage
    int idx4 = i << 2;                 // first pixel of this group
    int b = idx4 >> 18;                // batch index (HW = 2^18)
    int hw = idx4 & (HW - 1);          // offset within plane, multiple of 4
    const float* base = pred + (size_t)b * (NUM_CLASSES * HW) + hw;

    float4 best = *(const float4*)(base);
    int ax = 0, ay = 0, az = 0, aw = 0;
#pragma unroll
    for (int c = 1; c < NUM_CLASSES; ++c) {
      float4 v = *(const float4*)(base + (size_t)c * HW);
      // strict > keeps first occurrence of the max (jnp.argmax semantics)
      if (v.x > best.x) { best.x = v.x; ax = c; }
      if (v.y > best.y) { best.y = v.y; ay = c; }
      if (v.z > best.z) { best.z = v.z; az = c; }
      if (v.w > best.w) { best.w = v.w; aw = c; }
    }

    int4 t = *(const int4*)(target + idx4);
    atomicAdd(&lh[(ax << 4) + t.x], 1u);
    atomicAdd(&lh[(ay << 4) + t.y], 1u);
    atomicAdd(&lh[(az << 4) + t.z], 1u);
    atomicAdd(&lh[(aw << 4) + t.w], 1u);
  }

  __syncthreads();
  // plain coalesced store of this block's 256-bin partial histogram
  parts[blockIdx.x * 256 + threadIdx.x] = lh[threadIdx.x];
}

// Kernel 2: one 1024-thread block. Sum 1024 partial histograms (4 groups of
// 256 threads, coalesced column sums), then counts_p = row sums, counts_t =
// col sums, inter = diagonal; score = inter/union (1.0 if union==0); mean.
__global__ __launch_bounds__(1024) void jaccard_finalize_kernel(
    const unsigned int* __restrict__ parts, float* __restrict__ out) {
  __shared__ unsigned int acc[4][256];
  __shared__ unsigned int h[256];
  int t = threadIdx.x & 255;   // bin
  int g = threadIdx.x >> 8;    // group 0..3

  unsigned int s = 0;
#pragma unroll 8
  for (int r = g; r < HBLOCKS; r += 4)
    s += parts[r * 256 + t];   // consecutive t -> consecutive addresses
  acc[g][t] = s;
  __syncthreads();

  if (threadIdx.x < 256)
    h[threadIdx.x] = acc[0][threadIdx.x] + acc[1][threadIdx.x] +
                     acc[2][threadIdx.x] + acc[3][threadIdx.x];
  __syncthreads();

  if (threadIdx.x < 64) {
    int l = threadIdx.x;
    float score = 0.0f;
    if (l < NUM_CLASSES) {
      unsigned int cp = 0, ct = 0;
#pragma unroll
      for (int j = 0; j < NUM_CLASSES; ++j) {
        cp += h[l * 16 + j];   // pred == l
        ct += h[j * 16 + l];   // target == l
      }
      unsigned int inter = h[l * 17];  // pred == target == l
      float uni = (float)cp + (float)ct - (float)inter;
      score = (uni == 0.0f) ? 1.0f : ((float)inter / uni);
    }
    // reduce 16 partial scores in lanes 0..15 (lanes 16..63 contribute 0)
#pragma unroll
    for (int off = 8; off >= 1; off >>= 1) score += __shfl_down(score, off, 64);
    if (l == 0) out[0] = score * (1.0f / (float)NUM_CLASSES);
  }
}

extern "C" void kernel_launch(void* const* d_in, const int* in_sizes, int n_in,
                              void* d_out, int out_size, void* d_ws, size_t ws_size,
                              hipStream_t stream) {
  const float* pred = (const float*)d_in[0];
  const int* target = (const int*)d_in[1];
  float* out = (float*)d_out;
  unsigned int* parts = (unsigned int*)d_ws;  // 1024*256*4 B = 1 MiB used

  jaccard_hist_kernel<<<HBLOCKS, 256, 0, stream>>>(pred, target, parts);
  jaccard_finalize_kernel<<<1, 1024, 0, stream>>>(parts, out);
}